// Round 5
// baseline (314.805 us; speedup 1.0000x reference)
//
#include <hip/hip_runtime.h>
#include <math.h>

#define LROWS 16384
#define HDIM  1024
#define MDIM  2048
#define RSQRT_D 0.08838834764831844f   // 1/sqrt(128)

// ---- workspace layout (float offsets) ----
#define OFF_W     0          // w[8][2048]   (zeroed, atomic accum)
#define OFF_BETA  16384      // beta[8]      (zeroed, atomic accum)
#define OFF_Z     16392      // Z[8]         (zeroed, atomic accum)
#define OFF_Q     16400      // q[1024]
#define OFF_FEAT  17424      // feat[1024]
#define OFF_Y     18448      // y[8][2048]   (written by k4c)
#define OFF_YBUF  34832      // ybuf[512][8][2048]  (33.6 MB, written by k35)
// memset zeroes only [0, OFF_Q) = 65.6 KB

__device__ __forceinline__ float dot4(float4 a, float4 b) {
  return a.x * b.x + a.y * b.y + a.z * b.z + a.w * b.w;
}
__device__ __forceinline__ void fma4(float4& acc, float s, float4 v) {
  acc.x = fmaf(s, v.x, acc.x); acc.y = fmaf(s, v.y, acc.y);
  acc.z = fmaf(s, v.z, acc.z); acc.w = fmaf(s, v.w, acc.w);
}
__device__ __forceinline__ void add4(float4& a, float4 v) {
  a.x += v.x; a.y += v.y; a.z += v.z; a.w += v.w;
}

// K1: q[j] = x . Wq[j,:] + bq[j];  beta[j&7] += q[j]*bk[j]   (wave per output)
__global__ __launch_bounds__(256) void k1_q(const float* __restrict__ x,
                                            const float* __restrict__ Wq,
                                            const float* __restrict__ bq,
                                            const float* __restrict__ bk,
                                            float* __restrict__ ws) {
  int tid = threadIdx.x, lane = tid & 63;
  int j = blockIdx.x * 4 + (tid >> 6);
  const float4* xr = (const float4*)x;
  const float4* wr = (const float4*)(Wq + (size_t)j * HDIM);
  float acc = 0.f;
#pragma unroll
  for (int i = 0; i < 4; ++i) {
    int idx = i * 64 + lane;
    acc += dot4(xr[idx], wr[idx]);
  }
#pragma unroll
  for (int off = 32; off; off >>= 1) acc += __shfl_xor(acc, off);
  if (lane == 0) {
    float qj = acc + bq[j];
    ws[OFF_Q + j] = qj;
    atomicAdd(&ws[OFF_BETA + (j & 7)], qj * bk[j]);
  }
}

// K2: w[n][m] = sum_{c: c%8==n} q[c] * Wk[c][m]   (c-chunked, atomic accum)
__global__ __launch_bounds__(256) void k2_w(const float* __restrict__ Wk,
                                            float* __restrict__ ws) {
  int tid = threadIdx.x;
  int mc = blockIdx.x & 7, cc = blockIdx.x >> 3;
  int m = mc * 256 + tid;
  const float* q = ws + OFF_Q;
  float acc[8];
#pragma unroll
  for (int n = 0; n < 8; ++n) acc[n] = 0.f;
  int c0 = cc * 32;
  for (int c = c0; c < c0 + 32; c += 8) {
#pragma unroll
    for (int u = 0; u < 8; ++u)
      acc[u] = fmaf(q[c + u], Wk[(size_t)(c + u) * MDIM + m], acc[u]);
  }
#pragma unroll
  for (int n = 0; n < 8; ++n) atomicAdd(&ws[OFF_W + n * MDIM + m], acc[n]);
}

// K35: fused scores + exp + weighted sum. Wave = 512-col slab over all 32 rows.
// w-slab held in 64 VGPRs for the whole of phase A (no reloads); rows stream
// through a depth-4 rotating register pipeline (8 KB/wave in flight).
__global__ __launch_bounds__(256, 2) void k35(const float* __restrict__ mem,
                                              float* __restrict__ ws) {
  __shared__ float sred[4][32][8];   // 4 KB: per-wave slab-partial scores
  __shared__ float4 pv4[64];         // 1 KB: p[32 rows][8 heads]
  float* pvf = (float*)pv4;
  int tid = threadIdx.x, lane = tid & 63, wv = tid >> 6;
  int r0 = blockIdx.x * 32;
  int q0 = wv * 128 + lane;          // lane's first quad within the row (slab)
  const float4* W4 = (const float4*)(ws + OFF_W);   // head stride = 512 quads
  const float4* M4 = (const float4*)mem;            // row stride = 512 quads

  // ---- preload w slab: 8 heads x 2 quads = 64 VGPRs, lives all of phase A ----
  float4 wr[8][2];
#pragma unroll
  for (int n = 0; n < 8; ++n) {
    wr[n][0] = W4[n * 512 + q0];
    wr[n][1] = W4[n * 512 + q0 + 64];
  }

  // ---- phase A: scores, depth-4 row pipeline ----
  float4 mv[4][2];
#pragma unroll
  for (int k = 0; k < 4; ++k) {
    mv[k][0] = M4[(size_t)(r0 + k) * 512 + q0];
    mv[k][1] = M4[(size_t)(r0 + k) * 512 + q0 + 64];
  }
#pragma unroll 4
  for (int r = 0; r < 32; ++r) {
    int b = r & 3;
    float4 m0 = mv[b][0], m1 = mv[b][1];
    if (r + 4 < 32) {                 // refill slot: stays in flight ~3 rows
      mv[b][0] = M4[(size_t)(r0 + r + 4) * 512 + q0];
      mv[b][1] = M4[(size_t)(r0 + r + 4) * 512 + q0 + 64];
    }
    float a[8];
#pragma unroll
    for (int n = 0; n < 8; ++n) {
      float t;
      t = m0.x * wr[n][0].x;
      t = fmaf(m0.y, wr[n][0].y, t);
      t = fmaf(m0.z, wr[n][0].z, t);
      t = fmaf(m0.w, wr[n][0].w, t);
      t = fmaf(m1.x, wr[n][1].x, t);
      t = fmaf(m1.y, wr[n][1].y, t);
      t = fmaf(m1.z, wr[n][1].z, t);
      t = fmaf(m1.w, wr[n][1].w, t);
      a[n] = t;
    }
    // 64-lane allreduce (masks 1..8 lower to DPP/VALU; 16,32 to LDS pipe)
#pragma unroll
    for (int mask = 1; mask <= 32; mask <<= 1)
#pragma unroll
      for (int n = 0; n < 8; ++n) a[n] += __shfl_xor(a[n], mask);
    if (lane == 0) {
      *(float4*)&sred[wv][r][0] = make_float4(a[0], a[1], a[2], a[3]);
      *(float4*)&sred[wv][r][4] = make_float4(a[4], a[5], a[6], a[7]);
    }
  }
  __syncthreads();

  // ---- combine slabs + exp + Z: thread = (row, head) ----
  {
    int row = tid >> 3, h = tid & 7;
    float s = sred[0][row][h] + sred[1][row][h] + sred[2][row][h] + sred[3][row][h];
    s = (s + ws[OFF_BETA + h]) * RSQRT_D;
    float p = __expf(s);              // no max-shift: |s| provably < ~4
    pvf[tid] = p;
    float z = p;
    z += __shfl_xor(z, 8); z += __shfl_xor(z, 16); z += __shfl_xor(z, 32);
    if (lane < 8) atomicAdd(&ws[OFF_Z + lane], z);
  }
  __syncthreads();

  // ---- phase B: y-slab += p * mem-slab (rows L2/L3-hot), same pipeline ----
  float4 y[8][2];
#pragma unroll
  for (int n = 0; n < 8; ++n) {
    y[n][0] = make_float4(0.f, 0.f, 0.f, 0.f);
    y[n][1] = make_float4(0.f, 0.f, 0.f, 0.f);
  }
#pragma unroll
  for (int k = 0; k < 4; ++k) {
    mv[k][0] = M4[(size_t)(r0 + k) * 512 + q0];
    mv[k][1] = M4[(size_t)(r0 + k) * 512 + q0 + 64];
  }
#pragma unroll 4
  for (int r = 0; r < 32; ++r) {
    int b = r & 3;
    float4 m0 = mv[b][0], m1 = mv[b][1];
    if (r + 4 < 32) {
      mv[b][0] = M4[(size_t)(r0 + r + 4) * 512 + q0];
      mv[b][1] = M4[(size_t)(r0 + r + 4) * 512 + q0 + 64];
    }
    float4 pA = pv4[r * 2];           // LDS broadcast
    float4 pB = pv4[r * 2 + 1];
    fma4(y[0][0], pA.x, m0); fma4(y[0][1], pA.x, m1);
    fma4(y[1][0], pA.y, m0); fma4(y[1][1], pA.y, m1);
    fma4(y[2][0], pA.z, m0); fma4(y[2][1], pA.z, m1);
    fma4(y[3][0], pA.w, m0); fma4(y[3][1], pA.w, m1);
    fma4(y[4][0], pB.x, m0); fma4(y[4][1], pB.x, m1);
    fma4(y[5][0], pB.y, m0); fma4(y[5][1], pB.y, m1);
    fma4(y[6][0], pB.z, m0); fma4(y[6][1], pB.z, m1);
    fma4(y[7][0], pB.w, m0); fma4(y[7][1], pB.w, m1);
  }
  // spill y-slab to this block's private slot (no atomics)
  float4* YB4 = (float4*)(ws + OFF_YBUF + (size_t)blockIdx.x * 16384);
#pragma unroll
  for (int n = 0; n < 8; ++n) {
    YB4[n * 512 + q0] = y[n][0];
    YB4[n * 512 + q0 + 64] = y[n][1];
  }
}

// K4c: y[q] = sum_{b=0..511} ybuf[b][q]   (q = float4 index, 4096 total)
__global__ __launch_bounds__(256) void k4c(float* __restrict__ ws) {
  __shared__ float4 sA[256];
  int t = threadIdx.x;
  int quad = blockIdx.x * 16 + (t & 15);
  int b0 = (t >> 4) * 32;
  const float4* src = (const float4*)(ws + OFF_YBUF);
  float4 acc = make_float4(0.f, 0.f, 0.f, 0.f);
  for (int b = b0; b < b0 + 32; ++b)
    add4(acc, src[(size_t)b * 4096 + quad]);
  sA[(t & 15) * 16 + (t >> 4)] = acc;
  __syncthreads();
  if (t < 16) {
    float4 s = sA[t * 16];
#pragma unroll
    for (int j = 1; j < 16; ++j) add4(s, sA[t * 16 + j]);
    ((float4*)(ws + OFF_Y))[blockIdx.x * 16 + t] = s;
  }
}

// K6: feat[c] = (y[c&7] . Wv[c,:]) / Z[c&7] + bv[c]   (wave per c)
__global__ __launch_bounds__(256) void k6_feat(const float* __restrict__ Wv,
                                               const float* __restrict__ bv,
                                               float* __restrict__ ws) {
  int tid = threadIdx.x, lane = tid & 63;
  int c = blockIdx.x * 4 + (tid >> 6);
  int n = c & 7;
  const float4* yb = (const float4*)(ws + OFF_Y + n * MDIM);
  const float4* wb = (const float4*)(Wv + (size_t)c * MDIM);
  float acc = 0.f;
#pragma unroll
  for (int s = 0; s < 8; ++s) {
    int idx = s * 64 + lane;
    acc += dot4(yb[idx], wb[idx]);
  }
#pragma unroll
  for (int off = 32; off; off >>= 1) acc += __shfl_xor(acc, off);
  if (lane == 0) ws[OFF_FEAT + c] = acc / ws[OFF_Z + n] + bv[c];
}

// K7: out[j] = relu(x . Wo[j,0:1024] + feat . Wo[j,1024:2048] + bo[j]) (wave per j)
__global__ __launch_bounds__(256) void k7_out(const float* __restrict__ x,
                                              const float* __restrict__ Wo,
                                              const float* __restrict__ bo,
                                              const float* __restrict__ ws,
                                              float* __restrict__ out) {
  int tid = threadIdx.x, lane = tid & 63;
  int j = blockIdx.x * 4 + (tid >> 6);
  const float4* wb = (const float4*)(Wo + (size_t)j * 2048);
  const float4* xr = (const float4*)x;
  const float4* fr = (const float4*)(ws + OFF_FEAT);
  float acc = 0.f;
#pragma unroll
  for (int s = 0; s < 4; ++s) {
    int idx = s * 64 + lane;
    acc += dot4(xr[idx], wb[idx]);
    acc += dot4(fr[idx], wb[256 + idx]);
  }
#pragma unroll
  for (int off = 32; off; off >>= 1) acc += __shfl_xor(acc, off);
  if (lane == 0) out[j] = fmaxf(acc + bo[j], 0.f);
}

extern "C" void kernel_launch(void* const* d_in, const int* in_sizes, int n_in,
                              void* d_out, int out_size, void* d_ws, size_t ws_size,
                              hipStream_t stream) {
  const float* x   = (const float*)d_in[0];
  const float* mem = (const float*)d_in[1];
  const float* Wq  = (const float*)d_in[2];
  const float* bq  = (const float*)d_in[3];
  const float* Wk  = (const float*)d_in[4];
  const float* bk  = (const float*)d_in[5];
  const float* Wv  = (const float*)d_in[6];
  const float* bv  = (const float*)d_in[7];
  const float* Wo  = (const float*)d_in[8];
  const float* bo  = (const float*)d_in[9];
  float* ws  = (float*)d_ws;
  float* out = (float*)d_out;

  // zero w, beta, Z (65.6 KB)
  hipMemsetAsync(ws, 0, OFF_Q * sizeof(float), stream);

  k1_q   <<<256, 256, 0, stream>>>(x, Wq, bq, bk, ws);
  k2_w   <<<256, 256, 0, stream>>>(Wk, ws);
  k35    <<<512, 256, 0, stream>>>(mem, ws);
  k4c    <<<256, 256, 0, stream>>>(ws);
  k6_feat<<<256, 256, 0, stream>>>(Wv, bv, ws);
  k7_out <<<256, 256, 0, stream>>>(x, Wo, bo, ws, out);
}